// Round 3
// baseline (2330.793 us; speedup 1.0000x reference)
//
#include <hip/hip_runtime.h>
#include <hip/hip_bf16.h>
#include <math.h>

#define BATCH 64
#define LTOK  401
#define DMODEL 192
#define DINNER 384
#define DSTATE 16
#define DCONV 4
#define DTRANK 12
#define NCLS 1000
#define TOK (BATCH*LTOK)   /* 25664 */
#define EPSV 1e-5f

__device__ __forceinline__ float sigmoidf_(float x){ return 1.f/(1.f+__expf(-x)); }

/* ---------------- patch embed + pos embed + cls token ---------------- */
__global__ void embed_kernel(const float* __restrict__ imgs,
                             const float* __restrict__ pw,
                             const float* __restrict__ pb,
                             const float* __restrict__ pos,
                             const float* __restrict__ cls,
                             float* __restrict__ resid) {
  int idx = blockIdx.x*blockDim.x + threadIdx.x;
  if (idx >= TOK*DMODEL) return;
  int d = idx % DMODEL;
  int t = (idx / DMODEL) % LTOK;
  int b = idx / (DMODEL*LTOK);
  float v;
  if (t < LTOK-1) {
    const float* ip = imgs + (size_t)b*1600 + t*4;
    v = pb[d] + pos[(size_t)t*DMODEL + d];
    #pragma unroll
    for (int s=0;s<4;s++) v = fmaf(ip[s], pw[d*4+s], v);
  } else {
    v = cls[d] + pos[(size_t)(LTOK-1)*DMODEL + d];
  }
  resid[idx] = v;
}

/* ---------------- residual add + rmsnorm (one wave per token) ---------------- */
__global__ void addrms_kernel(const float* __restrict__ hidden,
                              float* __restrict__ resid,
                              const float* __restrict__ w,
                              float* __restrict__ normed,
                              int addHidden) {
  int t = blockIdx.x;
  int lane = threadIdx.x;            // 64
  size_t base = (size_t)t*DMODEL;
  float v[3]; float ss = 0.f;
  #pragma unroll
  for (int j=0;j<3;j++){
    int d = j*64 + lane;
    float x = resid[base+d];
    if (addHidden) x += hidden[base+d];
    v[j] = x; ss = fmaf(x, x, ss);
  }
  #pragma unroll
  for (int o=32;o>0;o>>=1) ss += __shfl_xor(ss, o, 64);
  float r = rsqrtf(ss*(1.f/DMODEL) + EPSV);
  #pragma unroll
  for (int j=0;j<3;j++){
    int d = j*64 + lane;
    if (addHidden) resid[base+d] = v[j];
    normed[base+d] = v[j]*r*w[d];
  }
}

/* ---------------- generic C = A @ W^T tiled GEMM (fp32) ----------------
   A: M x K (row stride lda), W: N x K (row stride ldw), C: M x N (row stride ldc)
   M must be a multiple of 64 (25664 = 401*64). N,K arbitrary-ish (K%16==0). */
__global__ void gemm_abt_kernel(const float* __restrict__ A, int lda,
                                const float* __restrict__ W, int ldw,
                                float* __restrict__ C, int ldc,
                                int N, int K) {
  __shared__ float As[16][65];
  __shared__ float Ws[16][65];
  int bm = blockIdx.y * 64;
  int bn = blockIdx.x * 64;
  int tid = threadIdx.x;             // 256
  int tr = tid >> 4, tc = tid & 15;  // 16x16 threads, 4x4 each
  int lr = tid >> 2;                 // 0..63
  int lk = (tid & 3) << 2;           // 0,4,8,12
  float acc[4][4] = {};
  for (int k0 = 0; k0 < K; k0 += 16) {
    float4 av = *reinterpret_cast<const float4*>(A + (size_t)(bm+lr)*lda + k0 + lk);
    float4 wv = make_float4(0.f,0.f,0.f,0.f);
    if (bn + lr < N)
      wv = *reinterpret_cast<const float4*>(W + (size_t)(bn+lr)*ldw + k0 + lk);
    As[lk+0][lr]=av.x; As[lk+1][lr]=av.y; As[lk+2][lr]=av.z; As[lk+3][lr]=av.w;
    Ws[lk+0][lr]=wv.x; Ws[lk+1][lr]=wv.y; Ws[lk+2][lr]=wv.z; Ws[lk+3][lr]=wv.w;
    __syncthreads();
    #pragma unroll
    for (int kk=0;kk<16;kk++){
      float ar[4], wr[4];
      #pragma unroll
      for (int i=0;i<4;i++) ar[i] = As[kk][tr*4+i];
      #pragma unroll
      for (int j=0;j<4;j++) wr[j] = Ws[kk][tc*4+j];
      #pragma unroll
      for (int i=0;i<4;i++)
        #pragma unroll
        for (int j=0;j<4;j++)
          acc[i][j] = fmaf(ar[i], wr[j], acc[i][j]);
    }
    __syncthreads();
  }
  #pragma unroll
  for (int i=0;i<4;i++){
    int m = bm + tr*4 + i;
    #pragma unroll
    for (int j=0;j<4;j++){
      int n = bn + tc*4 + j;
      if (n < N) C[(size_t)m*ldc + n] = acc[i][j];
    }
  }
}

/* ---------------- depthwise causal conv (k=4) + bias + silu ---------------- */
__global__ void conv_kernel(const float* __restrict__ xz,   // xm at cols [0,384), row stride 768
                            const float* __restrict__ cw,
                            const float* __restrict__ cb,
                            float* __restrict__ xconv) {
  int idx = blockIdx.x*blockDim.x + threadIdx.x;
  if (idx >= TOK*DINNER) return;
  int c = idx % DINNER;
  int l = (idx / DINNER) % LTOK;
  int b = idx / (DINNER*LTOK);
  const float* base = xz + (size_t)(b*LTOK)*768 + c;
  float acc = cb[c];
  #pragma unroll
  for (int k=0;k<DCONV;k++){
    int lt = l + k - (DCONV-1);
    if (lt >= 0) acc = fmaf(base[(size_t)lt*768], cw[c*DCONV+k], acc);
  }
  xconv[idx] = acc * sigmoidf_(acc);   // silu
}

/* ---------------- dt projection + softplus, writes into xz[:, :384] ---------------- */
__global__ void dt_kernel(const float* __restrict__ xdbl,
                          const float* __restrict__ dtw,
                          const float* __restrict__ dtb,
                          float* __restrict__ xz) {
  int idx = blockIdx.x*blockDim.x + threadIdx.x;
  if (idx >= TOK*DINNER) return;
  int c = idx % DINNER;
  int t = idx / DINNER;
  const float* xr = xdbl + (size_t)t*44;
  float acc = dtb[c];
  #pragma unroll
  for (int r=0;r<DTRANK;r++) acc = fmaf(xr[r], dtw[c*DTRANK+r], acc);
  float sp = (acc > 20.f) ? acc : log1pf(__expf(acc));
  xz[(size_t)t*768 + c] = sp;
}

/* ---------------- selective scan: one thread per (b, channel) ----------------
   reads x from xconv, dt from xz[:, ch], z from xz[:, 384+ch], B/C from xdbl.
   Fuses  y = (scan + x*Dskip) * silu(z). Writes y (row stride 384). */
__global__ void scan_kernel(const float* __restrict__ xconv,
                            const float* __restrict__ xz,
                            const float* __restrict__ xdbl,
                            const float* __restrict__ alog,
                            const float* __restrict__ dskip,
                            float* __restrict__ y) {
  int b  = blockIdx.x / 3;
  int ch = (blockIdx.x % 3)*128 + threadIdx.x;   // block=128, 384 = 3*128
  float Ast[DSTATE], h[DSTATE];
  #pragma unroll
  for (int s=0;s<DSTATE;s++){ Ast[s] = -__expf(alog[ch*DSTATE+s]); h[s]=0.f; }
  float dsk = dskip[ch];
  const float* xrow = xconv + (size_t)b*LTOK*DINNER + ch;
  const float* dz   = xz    + (size_t)b*LTOK*768;
  const float* bc   = xdbl  + (size_t)b*LTOK*44;
  float* yrow       = y     + (size_t)b*LTOK*DINNER + ch;
  for (int t=0;t<LTOK;t++){
    float xv  = xrow[(size_t)t*DINNER];
    float dtv = dz[(size_t)t*768 + ch];
    float zv  = dz[(size_t)t*768 + 384 + ch];
    float dx  = dtv*xv;
    const float* bct = bc + (size_t)t*44;
    float acc = 0.f;
    #pragma unroll
    for (int s=0;s<DSTATE;s++){
      float dA = __expf(dtv*Ast[s]);
      h[s] = fmaf(dA, h[s], dx*bct[12+s]);
      acc  = fmaf(h[s], bct[28+s], acc);
    }
    float yv = acc + xv*dsk;
    yrow[(size_t)t*DINNER] = yv * zv * sigmoidf_(zv);
  }
}

/* ---------------- final rmsnorm (last token) + classifier head ---------------- */
__global__ void head_kernel(const float* __restrict__ hidden,
                            const float* __restrict__ resid,
                            const float* __restrict__ normfw,
                            const float* __restrict__ headw,
                            const float* __restrict__ headb,
                            float* __restrict__ out) {
  int b = blockIdx.x;
  int tid = threadIdx.x;            // 256
  __shared__ float v[DMODEL];
  __shared__ float wsum[4];
  __shared__ float rshared;
  size_t base = ((size_t)b*LTOK + (LTOK-1))*DMODEL;
  float ss = 0.f;
  if (tid < DMODEL) {
    float hv = hidden[base+tid] + resid[base+tid];
    v[tid] = hv;
    ss = hv*hv;
  }
  #pragma unroll
  for (int o=32;o>0;o>>=1) ss += __shfl_xor(ss, o, 64);
  if ((tid & 63) == 0) wsum[tid>>6] = ss;
  __syncthreads();
  if (tid == 0) {
    float tot = wsum[0]+wsum[1]+wsum[2]+wsum[3];
    rshared = rsqrtf(tot*(1.f/DMODEL) + EPSV);
  }
  __syncthreads();
  float r = rshared;
  if (tid < DMODEL) v[tid] = v[tid]*r*normfw[tid];
  __syncthreads();
  for (int c=tid; c<NCLS; c+=256){
    float acc = headb[c];
    const float* wr = headw + (size_t)c*DMODEL;
    #pragma unroll 4
    for (int d=0;d<DMODEL;d++) acc = fmaf(v[d], wr[d], acc);
    out[(size_t)b*NCLS + c] = acc;
  }
}

extern "C" void kernel_launch(void* const* d_in, const int* in_sizes, int n_in,
                              void* d_out, int out_size, void* d_ws, size_t ws_size,
                              hipStream_t stream) {
  const float* imgs   = (const float*)d_in[0];
  const float* patchw = (const float*)d_in[1];
  const float* patchb = (const float*)d_in[2];
  const float* pos    = (const float*)d_in[3];
  const float* clstok = (const float*)d_in[4];
  const float* inw    = (const float*)d_in[5];
  const float* convw  = (const float*)d_in[6];
  const float* convb  = (const float*)d_in[7];
  const float* xpw    = (const float*)d_in[8];
  const float* dtw    = (const float*)d_in[9];
  const float* dtb    = (const float*)d_in[10];
  const float* alog   = (const float*)d_in[11];
  const float* dskip  = (const float*)d_in[12];
  const float* outw   = (const float*)d_in[13];
  const float* normw  = (const float*)d_in[14];
  const float* normfw = (const float*)d_in[15];
  const float* headw  = (const float*)d_in[16];
  const float* headb  = (const float*)d_in[17];
  float* out = (float*)d_out;

  /* workspace layout (floats) */
  float* ws     = (float*)d_ws;
  float* resid  = ws;                                 // TOK*192
  float* hidden = resid  + (size_t)TOK*DMODEL;        // TOK*192
  float* ny     = hidden + (size_t)TOK*DMODEL;        // TOK*384 (normed first 192-cols worth, then y)
  float* xzbuf  = ny     + (size_t)TOK*DINNER;        // TOK*768 (xm|z; xm half later reused for dt)
  float* xconv  = xzbuf  + (size_t)TOK*768;           // TOK*384
  float* xdbl   = xconv  + (size_t)TOK*DINNER;        // TOK*44

  embed_kernel<<<(TOK*DMODEL+255)/256, 256, 0, stream>>>(imgs, patchw, patchb, pos, clstok, resid);

  for (int i=0;i<4;i++){
    addrms_kernel<<<TOK, 64, 0, stream>>>(hidden, resid, normw + i*DMODEL, ny, i>0 ? 1 : 0);

    /* in_proj: (TOK x 192) @ (768 x 192)^T -> xz (TOK x 768) */
    gemm_abt_kernel<<<dim3(768/64, TOK/64), 256, 0, stream>>>(
        ny, DMODEL, inw + (size_t)i*768*DMODEL, DMODEL, xzbuf, 768, 768, DMODEL);

    conv_kernel<<<(TOK*DINNER+255)/256, 256, 0, stream>>>(
        xzbuf, convw + (size_t)i*DINNER*DCONV, convb + (size_t)i*DINNER, xconv);

    /* x_proj: (TOK x 384) @ (44 x 384)^T -> xdbl (TOK x 44) */
    gemm_abt_kernel<<<dim3(1, TOK/64), 256, 0, stream>>>(
        xconv, DINNER, xpw + (size_t)i*44*DINNER, DINNER, xdbl, 44, 44, DINNER);

    /* dt proj + softplus -> xz[:, :384] (xm half is dead after conv) */
    dt_kernel<<<(TOK*DINNER+255)/256, 256, 0, stream>>>(
        xdbl, dtw + (size_t)i*DINNER*DTRANK, dtb + (size_t)i*DINNER, xzbuf);

    /* selective scan + Dskip + silu(z) gate -> y (ny buffer) */
    scan_kernel<<<BATCH*3, 128, 0, stream>>>(
        xconv, xzbuf, xdbl, alog + (size_t)i*DINNER*DSTATE, dskip + (size_t)i*DINNER, ny);

    /* out_proj: (TOK x 384) @ (192 x 384)^T -> hidden (TOK x 192) */
    gemm_abt_kernel<<<dim3(DMODEL/64, TOK/64), 256, 0, stream>>>(
        ny, DINNER, outw + (size_t)i*DMODEL*DINNER, DINNER, hidden, DMODEL, DMODEL, DINNER);
  }

  head_kernel<<<BATCH, 256, 0, stream>>>(hidden, resid, normfw, headw, headb, out);
}